// Round 5
// baseline (88.255 us; speedup 1.0000x reference)
//
#include <hip/hip_runtime.h>

// LIF: v = v*0.5 + x_t; s = (v >= 1); v -= s   (DECAY=0.5 exact in fp32 -> bit-exact vs ref)
// x: (N=16, T=64, C=256, H=16, W=16) fp32 ; v_init: (N, C, H, W) fp32
// out: spikes (N, T, C, H, W) fp32
//
// R3 (kept): nontemporal stores -> write stream doesn't evict x from the
// 256 MB Infinity Cache across graph replays (FETCH 260->133 MB, -27% time).
// R4: TB 4->8 neutral -> per-wave MLP depth not the limiter.
// R5 experiment: float2 per thread -> 2x threads (524288, 2048 blocks,
// 8 blocks/CU, 32 waves/CU = full wave capacity). More independent streams
// for the memory controller; same coalescing (contiguous 8 B/lane).

typedef float f32x2 __attribute__((ext_vector_type(2)));

constexpr int T_STEPS = 64;
constexpr int SPATIAL = 256 * 16 * 16;   // C*H*W floats per (n,t) slice
constexpr int SPAT2   = SPATIAL / 2;     // 32768 float2 per slice
constexpr int N_BATCH = 16;
constexpr int TB      = 8;               // t-steps per load/store burst
constexpr int NT      = T_STEPS / TB;    // 8 bursts

__global__ __launch_bounds__(256, 8)
void lif_kernel(const f32x2* __restrict__ x,
                const f32x2* __restrict__ v_init,
                f32x2* __restrict__ out)
{
    const int gid = blockIdx.x * blockDim.x + threadIdx.x;  // float2 idx over (N, SPAT2)
    const int n   = gid >> 15;             // / 32768
    const int s2  = gid & (SPAT2 - 1);

    const int nbase = n * (T_STEPS * SPAT2);   // float2 units; max 33.5M fits int32
    const f32x2* __restrict__ xp = x   + nbase + s2;
    f32x2*       __restrict__ op = out + nbase + s2;

    f32x2 v = v_init[n * SPAT2 + s2];

    #pragma unroll
    for (int tb = 0; tb < NT; ++tb) {
        f32x2 b[TB];
        // burst-load TB slices (independent addresses -> deep vmcnt pipeline)
        #pragma unroll
        for (int k = 0; k < TB; ++k)
            b[k] = xp[(tb * TB + k) * SPAT2];

        // serial v-recurrence; overwrite b[k] with the spike (no extra regs)
        #pragma unroll
        for (int k = 0; k < TB; ++k) {
            f32x2 s;
            v.x = v.x * 0.5f + b[k].x;  s.x = (v.x >= 1.0f) ? 1.0f : 0.0f;  v.x -= s.x;
            v.y = v.y * 0.5f + b[k].y;  s.y = (v.y >= 1.0f) ? 1.0f : 0.0f;  v.y -= s.y;
            b[k] = s;
        }

        // burst-store TB slices, nontemporal (don't allocate in L2/L3)
        #pragma unroll
        for (int k = 0; k < TB; ++k)
            __builtin_nontemporal_store(b[k], &op[(tb * TB + k) * SPAT2]);
    }
}

extern "C" void kernel_launch(void* const* d_in, const int* in_sizes, int n_in,
                              void* d_out, int out_size, void* d_ws, size_t ws_size,
                              hipStream_t stream)
{
    const f32x2* x      = (const f32x2*)d_in[0];
    const f32x2* v_init = (const f32x2*)d_in[1];
    f32x2*       out    = (f32x2*)d_out;

    const int total2 = N_BATCH * SPAT2;     // 524288 threads
    const int block  = 256;
    const int grid   = total2 / block;      // 2048 blocks

    lif_kernel<<<grid, block, 0, stream>>>(x, v_init, out);
}

// Round 6
// 82.385 us; speedup vs baseline: 1.0713x; 1.0713x over previous
//
#include <hip/hip_runtime.h>

// LIF: v = v*0.5 + x_t; s = (v >= 1); v -= s   (DECAY=0.5 exact in fp32 -> bit-exact vs ref)
// x: (N=16, T=64, C=256, H=16, W=16) fp32 ; v_init: (N, C, H, W) fp32
// out: spikes (N, T, C, H, W) fp32
//
// Ledger:
// R3 (kept): nontemporal stores -> 256 MB write stream doesn't evict x
//   (x == 256 MB == L3 capacity) across graph replays. FETCH 260->133 MB,
//   115.6 -> 85.9 us.
// R4 (kept): TB=8 burst, float4/thread: 84.7 us. Best.
// R5 (reverted): float2/thread, 2x occupancy (53%) -> 88.3 us. Wave-level
//   parallelism is not the limiter.
// R6: revert to R4 + nt-load v_init (don't let its 4 MB compete with x in L3).
// State: 516 MB logical-min traffic, 6.09 TB/s aggregate = 97% of the
// 6.29 TB/s copy ceiling -> memory-system byte-limited.

typedef float f32x4 __attribute__((ext_vector_type(4)));

constexpr int T_STEPS = 64;
constexpr int SPATIAL = 256 * 16 * 16;   // C*H*W floats per (n,t) slice
constexpr int SPAT4   = SPATIAL / 4;     // 16384 float4 per slice
constexpr int N_BATCH = 16;
constexpr int TB      = 8;               // t-steps per load/store burst
constexpr int NT      = T_STEPS / TB;    // 8 bursts

__global__ __launch_bounds__(256, 8)
void lif_kernel(const f32x4* __restrict__ x,
                const f32x4* __restrict__ v_init,
                f32x4* __restrict__ out)
{
    const int gid = blockIdx.x * blockDim.x + threadIdx.x;  // float4 idx over (N, SPAT4)
    const int n   = gid >> 14;             // / 16384
    const int s4  = gid & (SPAT4 - 1);

    const int nbase = n * (T_STEPS * SPAT4);   // float4 units; max 16.7M fits int32
    const f32x4* __restrict__ xp = x   + nbase + s4;
    f32x4*       __restrict__ op = out + nbase + s4;

    // nt-load: v_init is streamed once; keep it out of L3 so x gets the space
    f32x4 v = __builtin_nontemporal_load(&v_init[n * SPAT4 + s4]);

    #pragma unroll
    for (int tb = 0; tb < NT; ++tb) {
        f32x4 b[TB];
        // burst-load TB slices (independent addresses -> deep vmcnt pipeline)
        #pragma unroll
        for (int k = 0; k < TB; ++k)
            b[k] = xp[(tb * TB + k) * SPAT4];

        // serial v-recurrence; overwrite b[k] with the spike (no extra regs)
        #pragma unroll
        for (int k = 0; k < TB; ++k) {
            f32x4 s;
            v.x = v.x * 0.5f + b[k].x;  s.x = (v.x >= 1.0f) ? 1.0f : 0.0f;  v.x -= s.x;
            v.y = v.y * 0.5f + b[k].y;  s.y = (v.y >= 1.0f) ? 1.0f : 0.0f;  v.y -= s.y;
            v.z = v.z * 0.5f + b[k].z;  s.z = (v.z >= 1.0f) ? 1.0f : 0.0f;  v.z -= s.z;
            v.w = v.w * 0.5f + b[k].w;  s.w = (v.w >= 1.0f) ? 1.0f : 0.0f;  v.w -= s.w;
            b[k] = s;
        }

        // burst-store TB slices, nontemporal (don't allocate in L2/L3)
        #pragma unroll
        for (int k = 0; k < TB; ++k)
            __builtin_nontemporal_store(b[k], &op[(tb * TB + k) * SPAT4]);
    }
}

extern "C" void kernel_launch(void* const* d_in, const int* in_sizes, int n_in,
                              void* d_out, int out_size, void* d_ws, size_t ws_size,
                              hipStream_t stream)
{
    const f32x4* x      = (const f32x4*)d_in[0];
    const f32x4* v_init = (const f32x4*)d_in[1];
    f32x4*       out    = (f32x4*)d_out;

    const int total4 = N_BATCH * SPAT4;     // 262144 threads
    const int block  = 256;
    const int grid   = total4 / block;      // 1024 blocks

    lif_kernel<<<grid, block, 0, stream>>>(x, v_init, out);
}